// Round 1
// baseline (2385.561 us; speedup 1.0000x reference)
//
#include <hip/hip_runtime.h>

// Problem dims (fixed)
#define Bc 2
#define Sc 2048
#define Dc 1024
#define Hc 16
#define Fc 64

constexpr int BHSF = Bc * Hc * Sc * Fc;   // 4,194,304 elements per [B,H,S,F] tensor

// ---------------------------------------------------------------------------
// Kernel 1: QKV projection.  out[b,h,s,f] = sum_d x[b,s,d] * W[h,d,f]
// grid (M/64=64, H=16, 3), block 256. 64x64 output tile, BK=32.
// ---------------------------------------------------------------------------
__global__ __launch_bounds__(256) void proj_kernel(
    const float* __restrict__ xq, const float* __restrict__ xk, const float* __restrict__ xv,
    const float* __restrict__ Wq, const float* __restrict__ Wk, const float* __restrict__ Wv,
    float* __restrict__ Qo, float* __restrict__ Ko, float* __restrict__ Vo)
{
    const float* x; const float* W; float* out;
    if (blockIdx.z == 0)      { x = xq; W = Wq; out = Qo; }
    else if (blockIdx.z == 1) { x = xk; W = Wk; out = Ko; }
    else                      { x = xv; W = Wv; out = Vo; }

    const int m0 = blockIdx.x * 64;
    const int h  = blockIdx.y;

    __shared__ float xs[64][33];   // +1 pad breaks bank collisions on column reads
    __shared__ float ws[32][65];

    const int t  = threadIdx.x;
    const int tx = t & 15, ty = t >> 4;

    float acc[4][4] = {{0.f}};

    for (int k0 = 0; k0 < Dc; k0 += 32) {
        __syncthreads();
        #pragma unroll
        for (int i = 0; i < 8; ++i) {
            int idx = t + i * 256;                       // 0..2047 : 64x32
            xs[idx >> 5][idx & 31] = x[(m0 + (idx >> 5)) * Dc + k0 + (idx & 31)];
        }
        #pragma unroll
        for (int i = 0; i < 8; ++i) {
            int idx = t + i * 256;                       // 0..2047 : 32x64
            ws[idx >> 6][idx & 63] = W[(h * Dc + k0 + (idx >> 6)) * Fc + (idx & 63)];
        }
        __syncthreads();
        #pragma unroll
        for (int kk = 0; kk < 32; ++kk) {
            float a[4], bb[4];
            #pragma unroll
            for (int i = 0; i < 4; ++i) a[i] = xs[ty + 16 * i][kk];
            #pragma unroll
            for (int j = 0; j < 4; ++j) bb[j] = ws[kk][tx + 16 * j];
            #pragma unroll
            for (int i = 0; i < 4; ++i)
                #pragma unroll
                for (int j = 0; j < 4; ++j)
                    acc[i][j] += a[i] * bb[j];
        }
    }

    #pragma unroll
    for (int i = 0; i < 4; ++i) {
        int m = m0 + ty + 16 * i;       // flat (b,s) row
        int b = m >> 11;                // / 2048
        int s = m & 2047;
        float* o = out + ((size_t)(b * Hc + h) * Sc + s) * Fc;
        #pragma unroll
        for (int j = 0; j < 4; ++j) o[tx + 16 * j] = acc[i][j];
    }
}

// ---------------------------------------------------------------------------
// Kernel 2: per-query-row softmax stats (m = rowmax, l = sum exp(s-m)) over k.
// grid (S/64=32, B*H=32), block 256. Each thread owns 1/4 of one q-row's ks.
// ---------------------------------------------------------------------------
__global__ __launch_bounds__(256) void stats_kernel(
    const float* __restrict__ Qg, const float* __restrict__ Kg,
    float* __restrict__ mrow, float* __restrict__ lrow)
{
    const int q0 = blockIdx.x * 64;
    const int bh = blockIdx.y;
    const float* Qb = Qg + (size_t)bh * Sc * Fc;
    const float* Kb = Kg + (size_t)bh * Sc * Fc;

    __shared__ float qs[64][68];   // stride 68: 16B-aligned float4 rows, banks spread by 4/row
    __shared__ float ks[64][68];

    const int t   = threadIdx.x;
    const int qr  = t >> 2;        // 0..63 query row in tile
    const int sub = t & 3;         // 4 threads share one q-row

    #pragma unroll
    for (int i = 0; i < 16; ++i) {
        int idx = t + i * 256;     // 64x64
        qs[idx >> 6][idx & 63] = Qb[(q0 + (idx >> 6)) * Fc + (idx & 63)];
    }

    float m = -1e30f, l = 0.f;

    for (int c0 = 0; c0 < Sc; c0 += 64) {
        __syncthreads();
        #pragma unroll
        for (int i = 0; i < 16; ++i) {
            int idx = t + i * 256;
            ks[idx >> 6][idx & 63] = Kb[(c0 + (idx >> 6)) * Fc + (idx & 63)];
        }
        __syncthreads();
        #pragma unroll
        for (int kc = 0; kc < 16; ++kc) {
            int kr = sub + 4 * kc;                 // 4 consecutive rows per lane-group
            float s = 0.f;
            #pragma unroll
            for (int f4 = 0; f4 < 64; f4 += 4) {
                float4 a = *(const float4*)&qs[qr][f4];
                float4 b = *(const float4*)&ks[kr][f4];
                s += a.x * b.x + a.y * b.y + a.z * b.z + a.w * b.w;
            }
            s *= 0.125f;                           // / sqrt(64)
            float d = s - m;
            if (d <= 0.f) {
                l += __expf(d);
            } else {
                l = l * __expf(-d) + 1.f;
                m = s;
            }
        }
    }

    // merge the 4 sub-lanes of each q-row (adjacent lanes in the same wave)
    #pragma unroll
    for (int off = 1; off < 4; off <<= 1) {
        float om = __shfl_xor(m, off);
        float ol = __shfl_xor(l, off);
        float nm = fmaxf(m, om);
        l = l * __expf(m - nm) + ol * __expf(om - nm);
        m = nm;
    }
    if (sub == 0) {
        mrow[bh * Sc + q0 + qr] = m;
        lrow[bh * Sc + q0 + qr] = l;
    }
}

// ---------------------------------------------------------------------------
// Kernel 3: O4[b,h,k,f] = sum_q softmax_row(q)[k] * V[b,h,q,f]   (A^T V)
// grid (S/64=32 k-tiles, B*H=32), block 256. q-chunks of 32 (LDS <= 64KB).
// ---------------------------------------------------------------------------
__global__ __launch_bounds__(256) void attn_out_kernel(
    const float* __restrict__ Qg, const float* __restrict__ Kg,
    const float* __restrict__ Vg, const float* __restrict__ mrow,
    const float* __restrict__ lrow, float* __restrict__ O4)
{
    const int k0 = blockIdx.x * 64;
    const int bh = blockIdx.y;
    const float* Qb = Qg + (size_t)bh * Sc * Fc;
    const float* Kb = Kg + (size_t)bh * Sc * Fc;
    const float* Vb = Vg + (size_t)bh * Sc * Fc;

    __shared__ float ks[64][68];   // this block's 64 K rows (resident all iterations)
    __shared__ float qs[32][68];
    __shared__ float vs[32][64];   // scalar reads only -> no pad needed
    __shared__ float ps[32][65];   // P[q][k], scalar access, +1 pad

    const int t   = threadIdx.x;
    const int tx  = t & 15, ty = t >> 4;
    const int qr  = t >> 3;        // 0..31
    const int sub = t & 7;

    float acc[4][4] = {{0.f}};

    #pragma unroll
    for (int i = 0; i < 16; ++i) {
        int idx = t + i * 256;
        ks[idx >> 6][idx & 63] = Kb[(k0 + (idx >> 6)) * Fc + (idx & 63)];
    }

    for (int q0 = 0; q0 < Sc; q0 += 32) {
        __syncthreads();           // protects qs/vs vs previous phase-B readers (and ks 1st iter)
        #pragma unroll
        for (int i = 0; i < 8; ++i) {
            int idx = t + i * 256; // 32x64
            int r = idx >> 6, c = idx & 63;
            qs[r][c] = Qb[(q0 + r) * Fc + c];
            vs[r][c] = Vb[(q0 + r) * Fc + c];
        }
        __syncthreads();

        // phase A: P^T tile. thread -> q-row qr, 8 k's
        float mq   = mrow[bh * Sc + q0 + qr];
        float invl = 1.0f / lrow[bh * Sc + q0 + qr];
        #pragma unroll
        for (int kc = 0; kc < 8; ++kc) {
            int kr = sub + 8 * kc;
            float s = 0.f;
            #pragma unroll
            for (int f4 = 0; f4 < 64; f4 += 4) {
                float4 a = *(const float4*)&qs[qr][f4];
                float4 b = *(const float4*)&ks[kr][f4];
                s += a.x * b.x + a.y * b.y + a.z * b.z + a.w * b.w;
            }
            ps[qr][kr] = __expf(s * 0.125f - mq) * invl;
        }
        __syncthreads();

        // phase B: acc[k,f] += sum_q P[q,k] * V[q,f]
        #pragma unroll
        for (int q = 0; q < 32; ++q) {
            float pa[4], vb[4];
            #pragma unroll
            for (int i = 0; i < 4; ++i) pa[i] = ps[q][ty + 16 * i];
            #pragma unroll
            for (int j = 0; j < 4; ++j) vb[j] = vs[q][tx + 16 * j];
            #pragma unroll
            for (int i = 0; i < 4; ++i)
                #pragma unroll
                for (int j = 0; j < 4; ++j)
                    acc[i][j] += pa[i] * vb[j];
        }
    }

    // write O4 in [b][h][k][f] contiguous order => raw-reshape faithful
    #pragma unroll
    for (int i = 0; i < 4; ++i) {
        int kk = k0 + ty + 16 * i;
        float* o = O4 + ((size_t)bh * Sc + kk) * Fc;
        #pragma unroll
        for (int j = 0; j < 4; ++j) o[tx + 16 * j] = acc[i][j];
    }
}

// ---------------------------------------------------------------------------
// Kernel 4: out = O4(viewed [B*2048, 1024]) @ Wo[1024,1024]
// grid (4096/64=64, 1024/64=16), block 256.
// ---------------------------------------------------------------------------
__global__ __launch_bounds__(256) void out_gemm_kernel(
    const float* __restrict__ A, const float* __restrict__ W,
    float* __restrict__ out)
{
    const int m0 = blockIdx.x * 64;
    const int n0 = blockIdx.y * 64;

    __shared__ float as_[64][33];
    __shared__ float ws_[32][65];

    const int t  = threadIdx.x;
    const int tx = t & 15, ty = t >> 4;

    float acc[4][4] = {{0.f}};

    for (int k0 = 0; k0 < 1024; k0 += 32) {
        __syncthreads();
        #pragma unroll
        for (int i = 0; i < 8; ++i) {
            int idx = t + i * 256;
            as_[idx >> 5][idx & 31] = A[(size_t)(m0 + (idx >> 5)) * 1024 + k0 + (idx & 31)];
        }
        #pragma unroll
        for (int i = 0; i < 8; ++i) {
            int idx = t + i * 256;
            ws_[idx >> 6][idx & 63] = W[(size_t)(k0 + (idx >> 6)) * 1024 + n0 + (idx & 63)];
        }
        __syncthreads();
        #pragma unroll
        for (int kk = 0; kk < 32; ++kk) {
            float a[4], bb[4];
            #pragma unroll
            for (int i = 0; i < 4; ++i) a[i] = as_[ty + 16 * i][kk];
            #pragma unroll
            for (int j = 0; j < 4; ++j) bb[j] = ws_[kk][tx + 16 * j];
            #pragma unroll
            for (int i = 0; i < 4; ++i)
                #pragma unroll
                for (int j = 0; j < 4; ++j)
                    acc[i][j] += a[i] * bb[j];
        }
    }

    #pragma unroll
    for (int i = 0; i < 4; ++i) {
        size_t row = m0 + ty + 16 * i;
        #pragma unroll
        for (int j = 0; j < 4; ++j)
            out[row * 1024 + n0 + tx + 16 * j] = acc[i][j];
    }
}

// ---------------------------------------------------------------------------
extern "C" void kernel_launch(void* const* d_in, const int* in_sizes, int n_in,
                              void* d_out, int out_size, void* d_ws, size_t ws_size,
                              hipStream_t stream) {
    const float* q  = (const float*)d_in[0];
    const float* k  = (const float*)d_in[1];
    const float* v  = (const float*)d_in[2];
    const float* Wq = (const float*)d_in[3];
    const float* Wk = (const float*)d_in[4];
    const float* Wv = (const float*)d_in[5];
    const float* Wo = (const float*)d_in[6];
    float* out = (float*)d_out;

    // workspace layout (fp32): Q | K | V | O4 | m | l   => ~64.5 MB
    float* Qw = (float*)d_ws;
    float* Kw = Qw + BHSF;
    float* Vw = Kw + BHSF;
    float* O4 = Vw + BHSF;
    float* mw = O4 + BHSF;
    float* lw = mw + Bc * Hc * Sc;

    proj_kernel<<<dim3(64, 16, 3), 256, 0, stream>>>(q, k, v, Wq, Wk, Wv, Qw, Kw, Vw);
    stats_kernel<<<dim3(32, 32), 256, 0, stream>>>(Qw, Kw, mw, lw);
    attn_out_kernel<<<dim3(32, 32), 256, 0, stream>>>(Qw, Kw, Vw, mw, lw, O4);
    out_gemm_kernel<<<dim3(64, 16), 256, 0, stream>>>(O4, Wo, out);
}

// Round 3
// 259.057 us; speedup vs baseline: 9.2086x; 9.2086x over previous
//
#include <hip/hip_runtime.h>
#include <stdint.h>

// Problem dims (fixed)
#define Bc 2
#define Sc 2048
#define Dc 1024
#define Hc 16
#define Fc 64
constexpr int BHSF = Bc * Hc * Sc * Fc;   // 4,194,304

typedef __attribute__((ext_vector_type(8))) short bf16x8;   // MFMA A/B frag (4 VGPR)
typedef __attribute__((ext_vector_type(4))) float f32x4;    // MFMA C/D frag

#define MFMA16(a, b, c) __builtin_amdgcn_mfma_f32_16x16x32_bf16(a, b, c, 0, 0, 0)
#define EXP2(x) __builtin_amdgcn_exp2f(x)
#define SCALE2 0.18033688f   /* 0.125 * log2(e) : softmax in base-2 domain */

__device__ inline short f2bf(float x) {           // fp32 -> bf16 rne
    uint32_t u = __builtin_bit_cast(uint32_t, x);
    u = (u + 0x7fffu + ((u >> 16) & 1u)) >> 16;
    return (short)u;
}

// ---------------------------------------------------------------------------
// K0: tiled transpose + fp32->bf16 convert:  in [z][M][N] f32 -> out [z][N][M] bf16
// grid (M/64, N/64, batch), block 256.
// ---------------------------------------------------------------------------
__global__ __launch_bounds__(256) void tcvt_kernel(
    const float* __restrict__ in, short* __restrict__ out, int M, int N)
{
    __shared__ short td[64 * 72];
    const int t = threadIdx.x;
    const int sr = t >> 2, sc = (t & 3) * 16;
    const int m0 = blockIdx.x * 64, n0 = blockIdx.y * 64;
    const size_t zoff = (size_t)blockIdx.z * M * N;

    const float* src = in + zoff + (size_t)(m0 + sr) * N + n0 + sc;
    #pragma unroll
    for (int i = 0; i < 16; i += 4) {
        f32x4 a = *(const f32x4*)(src + i);
        td[sr * 72 + sc + i + 0] = f2bf(a[0]);
        td[sr * 72 + sc + i + 1] = f2bf(a[1]);
        td[sr * 72 + sc + i + 2] = f2bf(a[2]);
        td[sr * 72 + sc + i + 3] = f2bf(a[3]);
    }
    __syncthreads();
    alignas(16) short vals[16];
    #pragma unroll
    for (int i = 0; i < 16; ++i) vals[i] = td[(sc + i) * 72 + sr];
    short* dst = out + zoff + (size_t)(n0 + sr) * M + m0 + sc;
    *(bf16x8*)dst       = *(const bf16x8*)&vals[0];
    *(bf16x8*)(dst + 8) = *(const bf16x8*)&vals[8];
}

// ---------------------------------------------------------------------------
// K1: QKV projection (NT MFMA: A = x rows, B = Wt rows).
// z=0 -> Q rows [b,h,s,f]; z=1 -> K rows; z=2 -> V TRANSPOSED [b,h,f,s].
// grid (64 m-tiles, 16 h, 3 z), 256 thr.
// ---------------------------------------------------------------------------
__global__ __launch_bounds__(256) void proj_kernel(
    const float* __restrict__ xq, const float* __restrict__ xk, const float* __restrict__ xv,
    const short* __restrict__ WqT, const short* __restrict__ WkT, const short* __restrict__ WvT,
    short* __restrict__ Qo, short* __restrict__ Ko, short* __restrict__ VtO)
{
    const float* x; const short* Wt;
    const int z = blockIdx.z;
    if (z == 0)      { x = xq; Wt = WqT; }
    else if (z == 1) { x = xk; Wt = WkT; }
    else             { x = xv; Wt = WvT; }
    const int m0 = blockIdx.x * 64;
    const int h  = blockIdx.y;
    const short* WtH = Wt + (size_t)h * Fc * Dc;   // [64 f][1024 d] bf16 rows

    __shared__ short xs[64 * 72];
    __shared__ short ws[64 * 72];

    const int t = threadIdx.x, lane = t & 63, w = t >> 6;
    const int l15 = lane & 15, g = lane >> 4;
    const int sr = t >> 2, sc = (t & 3) * 16;

    f32x4 acc[4];
    #pragma unroll
    for (int i = 0; i < 4; ++i) acc[i] = (f32x4){0.f, 0.f, 0.f, 0.f};

    for (int k0 = 0; k0 < Dc; k0 += 64) {
        __syncthreads();
        {   // stage X (fp32 -> bf16), rows of x
            const float* s = &x[(size_t)(m0 + sr) * Dc + k0 + sc];
            f32x4 a0 = ((const f32x4*)s)[0], a1 = ((const f32x4*)s)[1];
            f32x4 a2 = ((const f32x4*)s)[2], a3 = ((const f32x4*)s)[3];
            bf16x8 p0, p1;
            #pragma unroll
            for (int i = 0; i < 4; ++i) {
                p0[i] = f2bf(a0[i]); p0[4 + i] = f2bf(a1[i]);
                p1[i] = f2bf(a2[i]); p1[4 + i] = f2bf(a3[i]);
            }
            *(bf16x8*)&xs[sr * 72 + sc]     = p0;
            *(bf16x8*)&xs[sr * 72 + sc + 8] = p1;
        }
        // stage Wt rows (already bf16, already transposed)
        *(bf16x8*)&ws[sr * 72 + sc]     = *(const bf16x8*)&WtH[(size_t)sr * Dc + k0 + sc];
        *(bf16x8*)&ws[sr * 72 + sc + 8] = *(const bf16x8*)&WtH[(size_t)sr * Dc + k0 + sc + 8];
        __syncthreads();
        #pragma unroll
        for (int kc = 0; kc < 64; kc += 32) {
            bf16x8 af = *(const bf16x8*)&xs[(w * 16 + l15) * 72 + kc + g * 8];
            #pragma unroll
            for (int fb = 0; fb < 4; ++fb) {
                bf16x8 bfr = *(const bf16x8*)&ws[(fb * 16 + l15) * 72 + kc + g * 8];
                acc[fb] = MFMA16(af, bfr, acc[fb]);
            }
        }
    }

    // bounce accumulators through LDS for coalesced global writes
    __syncthreads();
    #pragma unroll
    for (int fb = 0; fb < 4; ++fb)
        #pragma unroll
        for (int r = 0; r < 4; ++r)
            xs[(w * 16 + g * 4 + r) * 72 + fb * 16 + l15] = f2bf(acc[fb][r]);
    __syncthreads();

    const int b = m0 >> 11, s0 = m0 & 2047;
    if (z < 2) {
        short* out = (z == 0) ? Qo : Ko;
        short* o = out + ((size_t)(b * Hc + h) * Sc + s0 + sr) * Fc;
        *(bf16x8*)&o[sc]     = *(const bf16x8*)&xs[sr * 72 + sc];
        *(bf16x8*)&o[sc + 8] = *(const bf16x8*)&xs[sr * 72 + sc + 8];
    } else {
        // Vt[b,h,f,s]: thread owns f = sr, s-cols sc..sc+15 (gather = transpose)
        alignas(16) short vals[16];
        #pragma unroll
        for (int i = 0; i < 16; ++i) vals[i] = xs[(sc + i) * 72 + sr];
        short* o = VtO + ((size_t)(b * Hc + h) * Fc + sr) * Sc + s0 + sc;
        *(bf16x8*)o       = *(const bf16x8*)&vals[0];
        *(bf16x8*)(o + 8) = *(const bf16x8*)&vals[8];
    }
}

// ---------------------------------------------------------------------------
// K2: softmax stats via S^T = mfma(K, Q). Lane's C column = one q; online
// (m,l) in-register; merge over lane groups (shfl_xor 16,32). Base-2 domain.
// grid (32 q-tiles, 32 bh), 256 thr.
// ---------------------------------------------------------------------------
__global__ __launch_bounds__(256) void stats_kernel(
    const short* __restrict__ Qg, const short* __restrict__ Kg,
    float* __restrict__ mrow, float* __restrict__ lrow)
{
    const int q0 = blockIdx.x * 64;
    const int bh = blockIdx.y;
    const short* Qb = Qg + (size_t)bh * Sc * Fc;
    const short* Kb = Kg + (size_t)bh * Sc * Fc;

    __shared__ short ks[64 * 72];

    const int t = threadIdx.x, lane = t & 63, w = t >> 6;
    const int l15 = lane & 15, g = lane >> 4;
    const int sr = t >> 2, sc = (t & 3) * 16;

    // resident Q B-frags (wave w owns q = q0 + 16w + l15)
    bf16x8 qf0 = *(const bf16x8*)&Qb[(size_t)(q0 + w * 16 + l15) * Fc + 0  + g * 8];
    bf16x8 qf1 = *(const bf16x8*)&Qb[(size_t)(q0 + w * 16 + l15) * Fc + 32 + g * 8];

    float m = -1e30f, l = 0.f;

    for (int kt = 0; kt < Sc; kt += 64) {
        __syncthreads();
        *(bf16x8*)&ks[sr * 72 + sc]     = *(const bf16x8*)&Kb[(size_t)(kt + sr) * Fc + sc];
        *(bf16x8*)&ks[sr * 72 + sc + 8] = *(const bf16x8*)&Kb[(size_t)(kt + sr) * Fc + sc + 8];
        __syncthreads();
        #pragma unroll
        for (int kf = 0; kf < 4; ++kf) {
            f32x4 acc = (f32x4){0.f, 0.f, 0.f, 0.f};
            bf16x8 a0 = *(const bf16x8*)&ks[(kf * 16 + l15) * 72 + 0  + g * 8];
            bf16x8 a1 = *(const bf16x8*)&ks[(kf * 16 + l15) * 72 + 32 + g * 8];
            acc = MFMA16(a0, qf0, acc);
            acc = MFMA16(a1, qf1, acc);     // same K-split chain order as attn recompute
            float s0 = acc[0] * SCALE2, s1 = acc[1] * SCALE2;
            float s2 = acc[2] * SCALE2, s3 = acc[3] * SCALE2;
            float tm = fmaxf(fmaxf(s0, s1), fmaxf(s2, s3));
            float mn = fmaxf(m, tm);
            l = l * EXP2(m - mn) + EXP2(s0 - mn) + EXP2(s1 - mn)
                                 + EXP2(s2 - mn) + EXP2(s3 - mn);
            m = mn;
        }
    }
    #pragma unroll
    for (int off = 16; off < 64; off <<= 1) {
        float om = __shfl_xor(m, off, 64);
        float ol = __shfl_xor(l, off, 64);
        float mn = fmaxf(m, om);
        l = l * EXP2(m - mn) + ol * EXP2(om - mn);
        m = mn;
    }
    if (lane < 16) {
        mrow[bh * Sc + q0 + w * 16 + l15] = m;
        lrow[bh * Sc + q0 + w * 16 + l15] = l;
    }
}

// ---------------------------------------------------------------------------
// K3: O4[b,h,k,f] = sum_q P[q,k] V[q,f].  Scores: S^T = mfma(K rows, Q rows).
// P^T staged [k][q] (scalar writes); PV = mfma(P^T rows, Vt rows). All frag
// reads are contiguous bf16x8 row reads.
// grid (32 k-tiles, 32 bh), 256 thr.
// ---------------------------------------------------------------------------
__global__ __launch_bounds__(256) void attn_kernel(
    const short* __restrict__ Qg, const short* __restrict__ Kg,
    const short* __restrict__ VtG, const float* __restrict__ mrow,
    const float* __restrict__ lrow, short* __restrict__ O4)
{
    const int k0 = blockIdx.x * 64;
    const int bh = blockIdx.y;
    const short* Qb = Qg  + (size_t)bh * Sc * Fc;
    const short* Kb = Kg  + (size_t)bh * Sc * Fc;
    const short* Vb = VtG + (size_t)bh * Fc * Sc;   // [64 f][2048 s]

    __shared__ short qs[64 * 72];   // Q rows (current q-chunk)
    __shared__ short vt[64 * 72];   // Vt rows [f][q-chunk]
    __shared__ short pl[64 * 72];   // P^T [k-local][q-chunk]; reused as out-bounce

    const int t = threadIdx.x, lane = t & 63, w = t >> 6;
    const int l15 = lane & 15, g = lane >> 4;
    const int sr = t >> 2, sc = (t & 3) * 16;

    // resident K A-frags (wave w owns k = k0 + 16w + l15)
    bf16x8 kf0 = *(const bf16x8*)&Kb[(size_t)(k0 + w * 16 + l15) * Fc + 0  + g * 8];
    bf16x8 kf1 = *(const bf16x8*)&Kb[(size_t)(k0 + w * 16 + l15) * Fc + 32 + g * 8];

    f32x4 oacc[4];
    #pragma unroll
    for (int i = 0; i < 4; ++i) oacc[i] = (f32x4){0.f, 0.f, 0.f, 0.f};

    for (int q0 = 0; q0 < Sc; q0 += 64) {
        __syncthreads();
        *(bf16x8*)&qs[sr * 72 + sc]     = *(const bf16x8*)&Qb[(size_t)(q0 + sr) * Fc + sc];
        *(bf16x8*)&qs[sr * 72 + sc + 8] = *(const bf16x8*)&Qb[(size_t)(q0 + sr) * Fc + sc + 8];
        *(bf16x8*)&vt[sr * 72 + sc]     = *(const bf16x8*)&Vb[(size_t)sr * Sc + q0 + sc];
        *(bf16x8*)&vt[sr * 72 + sc + 8] = *(const bf16x8*)&Vb[(size_t)sr * Sc + q0 + sc + 8];
        __syncthreads();

        // scores + P^T.  C: col=l15 -> q = q0+qf*16+l15; row=g*4+r -> k-local = w*16+g*4+r
        #pragma unroll
        for (int qf = 0; qf < 4; ++qf) {
            f32x4 acc = (f32x4){0.f, 0.f, 0.f, 0.f};
            bf16x8 b0 = *(const bf16x8*)&qs[(qf * 16 + l15) * 72 + 0  + g * 8];
            bf16x8 b1 = *(const bf16x8*)&qs[(qf * 16 + l15) * 72 + 32 + g * 8];
            acc = MFMA16(kf0, b0, acc);
            acc = MFMA16(kf1, b1, acc);     // identical chain to stats_kernel
            const int q = q0 + qf * 16 + l15;
            const float mq = mrow[bh * Sc + q];
            const float il = 1.f / lrow[bh * Sc + q];
            #pragma unroll
            for (int r = 0; r < 4; ++r)
                pl[(w * 16 + g * 4 + r) * 72 + qf * 16 + l15] =
                    f2bf(EXP2(acc[r] * SCALE2 - mq) * il);
        }
        __syncthreads();

        // PV: oacc[fb] += P^T[k, q-chunk] * V[q-chunk, f]
        #pragma unroll
        for (int qc = 0; qc < 64; qc += 32) {
            bf16x8 af = *(const bf16x8*)&pl[(w * 16 + l15) * 72 + qc + g * 8];
            #pragma unroll
            for (int fb = 0; fb < 4; ++fb) {
                bf16x8 bfr = *(const bf16x8*)&vt[(fb * 16 + l15) * 72 + qc + g * 8];
                oacc[fb] = MFMA16(af, bfr, oacc[fb]);
            }
        }
    }

    // epilogue: bounce via pl for coalesced bf16 stores
    __syncthreads();
    #pragma unroll
    for (int fb = 0; fb < 4; ++fb)
        #pragma unroll
        for (int r = 0; r < 4; ++r)
            pl[(w * 16 + g * 4 + r) * 72 + fb * 16 + l15] = f2bf(oacc[fb][r]);
    __syncthreads();
    short* o = O4 + ((size_t)bh * Sc + k0 + sr) * Fc;
    *(bf16x8*)&o[sc]     = *(const bf16x8*)&pl[sr * 72 + sc];
    *(bf16x8*)&o[sc + 8] = *(const bf16x8*)&pl[sr * 72 + sc + 8];
}

// ---------------------------------------------------------------------------
// K4: out(fp32) = O4_bf16 (flat [4096][1024]) @ Wo.  NT: B-frags = WoT rows.
// grid (64, 16), 256 thr.
// ---------------------------------------------------------------------------
__global__ __launch_bounds__(256) void outgemm_kernel(
    const short* __restrict__ A, const short* __restrict__ WoT, float* __restrict__ out)
{
    const int m0 = blockIdx.x * 64, n0 = blockIdx.y * 64;

    __shared__ short as_[64 * 72];
    __shared__ short ws[64 * 72];

    const int t = threadIdx.x, lane = t & 63, w = t >> 6;
    const int l15 = lane & 15, g = lane >> 4;
    const int sr = t >> 2, sc = (t & 3) * 16;

    f32x4 acc[4];
    #pragma unroll
    for (int i = 0; i < 4; ++i) acc[i] = (f32x4){0.f, 0.f, 0.f, 0.f};

    for (int k0 = 0; k0 < 1024; k0 += 64) {
        __syncthreads();
        *(bf16x8*)&as_[sr * 72 + sc]     = *(const bf16x8*)&A[(size_t)(m0 + sr) * 1024 + k0 + sc];
        *(bf16x8*)&as_[sr * 72 + sc + 8] = *(const bf16x8*)&A[(size_t)(m0 + sr) * 1024 + k0 + sc + 8];
        *(bf16x8*)&ws[sr * 72 + sc]      = *(const bf16x8*)&WoT[(size_t)(n0 + sr) * 1024 + k0 + sc];
        *(bf16x8*)&ws[sr * 72 + sc + 8]  = *(const bf16x8*)&WoT[(size_t)(n0 + sr) * 1024 + k0 + sc + 8];
        __syncthreads();
        #pragma unroll
        for (int kc = 0; kc < 64; kc += 32) {
            bf16x8 af = *(const bf16x8*)&as_[(w * 16 + l15) * 72 + kc + g * 8];
            #pragma unroll
            for (int nb = 0; nb < 4; ++nb) {
                bf16x8 bfr = *(const bf16x8*)&ws[(nb * 16 + l15) * 72 + kc + g * 8];
                acc[nb] = MFMA16(af, bfr, acc[nb]);
            }
        }
    }

    #pragma unroll
    for (int nb = 0; nb < 4; ++nb)
        #pragma unroll
        for (int r = 0; r < 4; ++r)
            out[(size_t)(m0 + w * 16 + g * 4 + r) * 1024 + n0 + nb * 16 + l15] = acc[nb][r];
}

// ---------------------------------------------------------------------------
extern "C" void kernel_launch(void* const* d_in, const int* in_sizes, int n_in,
                              void* d_out, int out_size, void* d_ws, size_t ws_size,
                              hipStream_t stream) {
    (void)in_sizes; (void)n_in; (void)out_size; (void)ws_size;
    const float* q  = (const float*)d_in[0];
    const float* k  = (const float*)d_in[1];
    const float* v  = (const float*)d_in[2];
    const float* Wq = (const float*)d_in[3];
    const float* Wk = (const float*)d_in[4];
    const float* Wv = (const float*)d_in[5];
    const float* Wo = (const float*)d_in[6];
    float* out = (float*)d_out;

    // ws: bf16 Q | K | Vt | O4 (4M shorts each) | WqT | WkT | WvT | WoT (1M each)
    //     | f32 m | l.   Total ~40.5 MB.
    short* Qw  = (short*)d_ws;
    short* Kw  = Qw  + BHSF;
    short* Vt  = Kw  + BHSF;
    short* O4  = Vt  + BHSF;
    short* WqT = O4  + BHSF;
    short* WkT = WqT + Hc * Dc * Fc;
    short* WvT = WkT + Hc * Dc * Fc;
    short* WoT = WvT + Hc * Dc * Fc;
    float* mw  = (float*)(WoT + Dc * Dc);
    float* lw  = mw + Bc * Hc * Sc;

    tcvt_kernel<<<dim3(16, 1, 16), 256, 0, stream>>>(Wq, WqT, Dc, Fc);
    tcvt_kernel<<<dim3(16, 1, 16), 256, 0, stream>>>(Wk, WkT, Dc, Fc);
    tcvt_kernel<<<dim3(16, 1, 16), 256, 0, stream>>>(Wv, WvT, Dc, Fc);
    tcvt_kernel<<<dim3(16, 16, 1), 256, 0, stream>>>(Wo, WoT, Dc, Dc);
    proj_kernel<<<dim3(64, 16, 3), 256, 0, stream>>>(q, k, v, WqT, WkT, WvT, Qw, Kw, Vt);
    stats_kernel<<<dim3(32, 32), 256, 0, stream>>>(Qw, Kw, mw, lw);
    attn_kernel<<<dim3(32, 32), 256, 0, stream>>>(Qw, Kw, Vt, mw, lw, O4);
    outgemm_kernel<<<dim3(64, 16), 256, 0, stream>>>(O4, WoT, out);
}

// Round 4
// 210.503 us; speedup vs baseline: 11.3327x; 1.2307x over previous
//
#include <hip/hip_runtime.h>
#include <stdint.h>

// Problem dims (fixed)
#define Bc 2
#define Sc 2048
#define Dc 1024
#define Hc 16
#define Fc 64
constexpr int BHSF = Bc * Hc * Sc * Fc;   // 4,194,304

typedef __attribute__((ext_vector_type(8))) short bf16x8;   // MFMA A/B frag (4 VGPR)
typedef __attribute__((ext_vector_type(4))) float f32x4;    // MFMA C/D frag

#define MFMA16(a, b, c) __builtin_amdgcn_mfma_f32_16x16x32_bf16(a, b, c, 0, 0, 0)
#define EXP2(x) __builtin_amdgcn_exp2f(x)
#define SCALE2 0.18033688f   /* 0.125 * log2(e) : softmax in base-2 domain */

__device__ inline short f2bf(float x) {           // fp32 -> bf16 rne
    uint32_t u = __builtin_bit_cast(uint32_t, x);
    u = (u + 0x7fffu + ((u >> 16) & 1u)) >> 16;
    return (short)u;
}

// ---------------------------------------------------------------------------
// K0a: elementwise fp32 -> bf16 for q,k,v into Xb[3][4096][1024]
// grid (1024, 3), 256 thr, 16 elems/thr.
// ---------------------------------------------------------------------------
__global__ __launch_bounds__(256) void xcvt_kernel(
    const float* __restrict__ a, const float* __restrict__ b,
    const float* __restrict__ c, short* __restrict__ out)
{
    const float* src = (blockIdx.y == 0) ? a : (blockIdx.y == 1) ? b : c;
    const size_t base = (size_t)blockIdx.x * 4096 + threadIdx.x * 16;
    const float* s = src + base;
    short* d = out + (size_t)blockIdx.y * 4096 * 1024 + base;
    f32x4 v0 = ((const f32x4*)s)[0], v1 = ((const f32x4*)s)[1];
    f32x4 v2 = ((const f32x4*)s)[2], v3 = ((const f32x4*)s)[3];
    bf16x8 p0, p1;
    #pragma unroll
    for (int i = 0; i < 4; ++i) {
        p0[i] = f2bf(v0[i]); p0[4 + i] = f2bf(v1[i]);
        p1[i] = f2bf(v2[i]); p1[4 + i] = f2bf(v3[i]);
    }
    *(bf16x8*)d       = p0;
    *(bf16x8*)(d + 8) = p1;
}

// ---------------------------------------------------------------------------
// K0b: tiled transpose + fp32->bf16:  in [z][M][N] f32 -> out [z][N][M] bf16
// ---------------------------------------------------------------------------
__global__ __launch_bounds__(256) void tcvt_kernel(
    const float* __restrict__ in, short* __restrict__ out, int M, int N)
{
    __shared__ short td[64 * 72];
    const int t = threadIdx.x;
    const int sr = t >> 2, sc = (t & 3) * 16;
    const int m0 = blockIdx.x * 64, n0 = blockIdx.y * 64;
    const size_t zoff = (size_t)blockIdx.z * M * N;

    const float* src = in + zoff + (size_t)(m0 + sr) * N + n0 + sc;
    #pragma unroll
    for (int i = 0; i < 16; i += 4) {
        f32x4 a = *(const f32x4*)(src + i);
        td[sr * 72 + sc + i + 0] = f2bf(a[0]);
        td[sr * 72 + sc + i + 1] = f2bf(a[1]);
        td[sr * 72 + sc + i + 2] = f2bf(a[2]);
        td[sr * 72 + sc + i + 3] = f2bf(a[3]);
    }
    __syncthreads();
    alignas(16) short vals[16];
    #pragma unroll
    for (int i = 0; i < 16; ++i) vals[i] = td[(sc + i) * 72 + sr];
    short* dst = out + zoff + (size_t)(n0 + sr) * M + m0 + sc;
    *(bf16x8*)dst       = *(const bf16x8*)&vals[0];
    *(bf16x8*)(dst + 8) = *(const bf16x8*)&vals[8];
}

// ---------------------------------------------------------------------------
// K1: QKV projection. NT MFMA: A = Xb rows, B = Wt rows. m-tile 256 (msub=4),
// h is the FASTEST grid dim so 16 consecutive blocks share each x slab in L2.
// z=0 Q rows, z=1 K rows, z=2 V transposed [b,h,f,s].
// grid (16 h, 16 mt, 3 z), 256 thr.
// ---------------------------------------------------------------------------
__global__ __launch_bounds__(256) void proj_kernel(
    const short* __restrict__ Xb,
    const short* __restrict__ WqT, const short* __restrict__ WkT,
    const short* __restrict__ WvT,
    short* __restrict__ Qo, short* __restrict__ Ko, short* __restrict__ VtO)
{
    const int z = blockIdx.z, h = blockIdx.x, mt = blockIdx.y;
    const short* X  = Xb + (size_t)z * 4096 * Dc;
    const short* Wt = ((z == 0) ? WqT : (z == 1) ? WkT : WvT) + (size_t)h * Fc * Dc;
    const int m0 = mt * 256;

    __shared__ short xs[256 * 72];
    __shared__ short ws[64 * 72];

    const int t = threadIdx.x, lane = t & 63, w = t >> 6;
    const int l15 = lane & 15, g = lane >> 4;
    const int sr4 = t >> 2, sc4 = (t & 3) * 16;

    f32x4 acc[4][4];
    #pragma unroll
    for (int i = 0; i < 4; ++i)
        #pragma unroll
        for (int j = 0; j < 4; ++j) acc[i][j] = (f32x4){0.f, 0.f, 0.f, 0.f};

    for (int d0 = 0; d0 < Dc; d0 += 64) {
        __syncthreads();
        #pragma unroll
        for (int i = 0; i < 4; ++i) {
            int r = sr4 + 64 * i;
            const short* s = &X[(size_t)(m0 + r) * Dc + d0 + sc4];
            *(bf16x8*)&xs[r * 72 + sc4]     = *(const bf16x8*)s;
            *(bf16x8*)&xs[r * 72 + sc4 + 8] = *(const bf16x8*)(s + 8);
        }
        {
            const short* s = &Wt[(size_t)sr4 * Dc + d0 + sc4];
            *(bf16x8*)&ws[sr4 * 72 + sc4]     = *(const bf16x8*)s;
            *(bf16x8*)&ws[sr4 * 72 + sc4 + 8] = *(const bf16x8*)(s + 8);
        }
        __syncthreads();
        #pragma unroll
        for (int kc = 0; kc < 64; kc += 32) {
            bf16x8 bfr[4], afr[4];
            #pragma unroll
            for (int fb = 0; fb < 4; ++fb)
                bfr[fb] = *(const bf16x8*)&ws[(fb * 16 + l15) * 72 + kc + g * 8];
            #pragma unroll
            for (int ms = 0; ms < 4; ++ms)
                afr[ms] = *(const bf16x8*)&xs[(w * 64 + ms * 16 + l15) * 72 + kc + g * 8];
            #pragma unroll
            for (int ms = 0; ms < 4; ++ms)
                #pragma unroll
                for (int fb = 0; fb < 4; ++fb)
                    acc[ms][fb] = MFMA16(afr[ms], bfr[fb], acc[ms][fb]);
        }
    }

    // bounce accs through xs (viewed [256][72]) for coalesced stores
    __syncthreads();
    #pragma unroll
    for (int ms = 0; ms < 4; ++ms)
        #pragma unroll
        for (int fb = 0; fb < 4; ++fb)
            #pragma unroll
            for (int r = 0; r < 4; ++r)
                xs[(w * 64 + ms * 16 + g * 4 + r) * 72 + fb * 16 + l15] = f2bf(acc[ms][fb][r]);
    __syncthreads();

    const int b = m0 >> 11, s0 = m0 & 2047;
    if (z < 2) {
        short* outp = ((z == 0) ? Qo : Ko) + ((size_t)(b * Hc + h) * Sc + s0) * Fc;
        #pragma unroll
        for (int i = 0; i < 4; ++i) {
            int r = sr4 + 64 * i;
            *(bf16x8*)&outp[(size_t)r * Fc + sc4]     = *(const bf16x8*)&xs[r * 72 + sc4];
            *(bf16x8*)&outp[(size_t)r * Fc + sc4 + 8] = *(const bf16x8*)&xs[r * 72 + sc4 + 8];
        }
    } else {
        // Vt[b,h,f,s]: thread owns f-row sr4/... gather columns (transpose)
        const int fr = t >> 2;
        short* o = VtO + ((size_t)(b * Hc + h) * Fc + fr) * Sc + s0;
        #pragma unroll
        for (int i = 0; i < 4; ++i) {
            int scol = (t & 3) * 16 + 64 * i;
            alignas(16) short vals[16];
            #pragma unroll
            for (int j = 0; j < 16; ++j) vals[j] = xs[(scol + j) * 72 + fr];
            *(bf16x8*)&o[scol]     = *(const bf16x8*)&vals[0];
            *(bf16x8*)&o[scol + 8] = *(const bf16x8*)&vals[8];
        }
    }
}

// ---------------------------------------------------------------------------
// K2: softmax stats. S^T = mfma(K rows, Q rows); lane col = q. Wave holds 2
// resident q-subtiles (32 q). Writes fused m' = m + log2(l).
// grid (16 q-tiles of 128, 32 bh), 256 thr.
// ---------------------------------------------------------------------------
__global__ __launch_bounds__(256) void stats_kernel(
    const short* __restrict__ Qg, const short* __restrict__ Kg,
    float* __restrict__ mrow)
{
    const int q0 = blockIdx.x * 128;
    const int bh = blockIdx.y;
    const short* Qb = Qg + (size_t)bh * Sc * Fc;
    const short* Kb = Kg + (size_t)bh * Sc * Fc;

    __shared__ short ks[64 * 72];

    const int t = threadIdx.x, lane = t & 63, w = t >> 6;
    const int l15 = lane & 15, g = lane >> 4;
    const int sr4 = t >> 2, sc4 = (t & 3) * 16;

    bf16x8 qf[2][2];
    #pragma unroll
    for (int qs2 = 0; qs2 < 2; ++qs2)
        #pragma unroll
        for (int kc2 = 0; kc2 < 2; ++kc2)
            qf[qs2][kc2] = *(const bf16x8*)
                &Qb[(size_t)(q0 + w * 32 + qs2 * 16 + l15) * Fc + kc2 * 32 + g * 8];

    float m[2] = {-1e30f, -1e30f}, l[2] = {0.f, 0.f};

    for (int kt = 0; kt < Sc; kt += 64) {
        __syncthreads();
        {
            const short* s = &Kb[(size_t)(kt + sr4) * Fc + sc4];
            *(bf16x8*)&ks[sr4 * 72 + sc4]     = *(const bf16x8*)s;
            *(bf16x8*)&ks[sr4 * 72 + sc4 + 8] = *(const bf16x8*)(s + 8);
        }
        __syncthreads();
        #pragma unroll
        for (int kf = 0; kf < 4; ++kf) {
            bf16x8 a0 = *(const bf16x8*)&ks[(kf * 16 + l15) * 72 + 0  + g * 8];
            bf16x8 a1 = *(const bf16x8*)&ks[(kf * 16 + l15) * 72 + 32 + g * 8];
            #pragma unroll
            for (int qs2 = 0; qs2 < 2; ++qs2) {
                f32x4 acc = (f32x4){0.f, 0.f, 0.f, 0.f};
                acc = MFMA16(a0, qf[qs2][0], acc);
                acc = MFMA16(a1, qf[qs2][1], acc);   // same split order as attn
                float s0 = acc[0] * SCALE2, s1 = acc[1] * SCALE2;
                float s2 = acc[2] * SCALE2, s3 = acc[3] * SCALE2;
                float tm = fmaxf(fmaxf(s0, s1), fmaxf(s2, s3));
                float mn = fmaxf(m[qs2], tm);
                l[qs2] = l[qs2] * EXP2(m[qs2] - mn) + EXP2(s0 - mn) + EXP2(s1 - mn)
                                                    + EXP2(s2 - mn) + EXP2(s3 - mn);
                m[qs2] = mn;
            }
        }
    }
    #pragma unroll
    for (int qs2 = 0; qs2 < 2; ++qs2) {
        #pragma unroll
        for (int off = 16; off < 64; off <<= 1) {
            float om = __shfl_xor(m[qs2], off, 64);
            float ol = __shfl_xor(l[qs2], off, 64);
            float mn = fmaxf(m[qs2], om);
            l[qs2] = l[qs2] * EXP2(m[qs2] - mn) + ol * EXP2(om - mn);
            m[qs2] = mn;
        }
        if (lane < 16)
            mrow[bh * Sc + q0 + w * 32 + qs2 * 16 + l15] = m[qs2] + __log2f(l[qs2]);
    }
}

// ---------------------------------------------------------------------------
// K3: O4[b,h,k,f] = sum_q P[q,k] V[q,f]. Wave owns 32 k-rows (K-frags
// resident, 2 ksub); k-tile 128. P = exp2(s*SCALE2 - m') with m' staged in LDS.
// grid (16 k-tiles, 32 bh), 256 thr.
// ---------------------------------------------------------------------------
__global__ __launch_bounds__(256) void attn_kernel(
    const short* __restrict__ Qg, const short* __restrict__ Kg,
    const short* __restrict__ VtG, const float* __restrict__ mrow,
    short* __restrict__ O4)
{
    const int k0 = blockIdx.x * 128;
    const int bh = blockIdx.y;
    const short* Qb = Qg  + (size_t)bh * Sc * Fc;
    const short* Kb = Kg  + (size_t)bh * Sc * Fc;
    const short* Vb = VtG + (size_t)bh * Fc * Sc;   // [64 f][2048 s]

    __shared__ short qs[64 * 72];
    __shared__ short vt[64 * 72];
    __shared__ short pl[128 * 72];   // P^T [k-local][q-chunk]; reused as out-bounce
    __shared__ float msh[2048];      // fused m' per q

    const int t = threadIdx.x, lane = t & 63, w = t >> 6;
    const int l15 = lane & 15, g = lane >> 4;
    const int sr4 = t >> 2, sc4 = (t & 3) * 16;

    // stage m' (covered by the first stage-barrier below)
    *(f32x4*)&msh[t * 8]     = *(const f32x4*)&mrow[bh * Sc + t * 8];
    *(f32x4*)&msh[t * 8 + 4] = *(const f32x4*)&mrow[bh * Sc + t * 8 + 4];

    // resident K A-frags: wave w owns k-rows k0 + w*32 + ksub*16 + l15
    bf16x8 kf[2][2];
    #pragma unroll
    for (int ks2 = 0; ks2 < 2; ++ks2)
        #pragma unroll
        for (int kc2 = 0; kc2 < 2; ++kc2)
            kf[ks2][kc2] = *(const bf16x8*)
                &Kb[(size_t)(k0 + w * 32 + ks2 * 16 + l15) * Fc + kc2 * 32 + g * 8];

    f32x4 oacc[2][4];
    #pragma unroll
    for (int i = 0; i < 2; ++i)
        #pragma unroll
        for (int j = 0; j < 4; ++j) oacc[i][j] = (f32x4){0.f, 0.f, 0.f, 0.f};

    for (int q0 = 0; q0 < Sc; q0 += 64) {
        __syncthreads();
        {
            const short* s = &Qb[(size_t)(q0 + sr4) * Fc + sc4];
            *(bf16x8*)&qs[sr4 * 72 + sc4]     = *(const bf16x8*)s;
            *(bf16x8*)&qs[sr4 * 72 + sc4 + 8] = *(const bf16x8*)(s + 8);
            const short* v = &Vb[(size_t)sr4 * Sc + q0 + sc4];
            *(bf16x8*)&vt[sr4 * 72 + sc4]     = *(const bf16x8*)v;
            *(bf16x8*)&vt[sr4 * 72 + sc4 + 8] = *(const bf16x8*)(v + 8);
        }
        __syncthreads();

        // scores + P^T  (lane col = q = q0 + qf*16 + l15)
        #pragma unroll
        for (int qf = 0; qf < 4; ++qf) {
            bf16x8 b0 = *(const bf16x8*)&qs[(qf * 16 + l15) * 72 + 0  + g * 8];
            bf16x8 b1 = *(const bf16x8*)&qs[(qf * 16 + l15) * 72 + 32 + g * 8];
            const float mq2 = msh[q0 + qf * 16 + l15];
            #pragma unroll
            for (int ks2 = 0; ks2 < 2; ++ks2) {
                f32x4 acc = (f32x4){0.f, 0.f, 0.f, 0.f};
                acc = MFMA16(kf[ks2][0], b0, acc);
                acc = MFMA16(kf[ks2][1], b1, acc);
                #pragma unroll
                for (int r = 0; r < 4; ++r)
                    pl[(w * 32 + ks2 * 16 + g * 4 + r) * 72 + qf * 16 + l15] =
                        f2bf(EXP2(acc[r] * SCALE2 - mq2));
            }
        }
        __syncthreads();

        // PV
        #pragma unroll
        for (int qc = 0; qc < 64; qc += 32) {
            bf16x8 pa[2], vb[4];
            #pragma unroll
            for (int ks2 = 0; ks2 < 2; ++ks2)
                pa[ks2] = *(const bf16x8*)&pl[(w * 32 + ks2 * 16 + l15) * 72 + qc + g * 8];
            #pragma unroll
            for (int fb = 0; fb < 4; ++fb)
                vb[fb] = *(const bf16x8*)&vt[(fb * 16 + l15) * 72 + qc + g * 8];
            #pragma unroll
            for (int ks2 = 0; ks2 < 2; ++ks2)
                #pragma unroll
                for (int fb = 0; fb < 4; ++fb)
                    oacc[ks2][fb] = MFMA16(pa[ks2], vb[fb], oacc[ks2][fb]);
        }
    }

    // epilogue: bounce via pl for coalesced bf16 stores (128 rows x 64)
    __syncthreads();
    #pragma unroll
    for (int ks2 = 0; ks2 < 2; ++ks2)
        #pragma unroll
        for (int fb = 0; fb < 4; ++fb)
            #pragma unroll
            for (int r = 0; r < 4; ++r)
                pl[(w * 32 + ks2 * 16 + g * 4 + r) * 72 + fb * 16 + l15] =
                    f2bf(oacc[ks2][fb][r]);
    __syncthreads();
    {
        const int sr2 = t >> 1, sc2 = (t & 1) * 32;
        short* o = O4 + ((size_t)bh * Sc + k0 + sr2) * Fc + sc2;
        #pragma unroll
        for (int i = 0; i < 32; i += 8)
            *(bf16x8*)&o[i] = *(const bf16x8*)&pl[sr2 * 72 + sc2 + i];
    }
}

// ---------------------------------------------------------------------------
// K4: out(fp32) = O4 (flat [4096][1024] bf16) @ Wo. NT: B = WoT rows.
// m-tile 128 (msub=2). grid (32 mt, 16 nt), 256 thr.
// ---------------------------------------------------------------------------
__global__ __launch_bounds__(256) void outgemm_kernel(
    const short* __restrict__ A, const short* __restrict__ WoT,
    float* __restrict__ out)
{
    const int m0 = blockIdx.x * 128, n0 = blockIdx.y * 64;

    __shared__ short as_[128 * 72];
    __shared__ short ws[64 * 72];

    const int t = threadIdx.x, lane = t & 63, w = t >> 6;
    const int l15 = lane & 15, g = lane >> 4;
    const int sr4 = t >> 2, sc4 = (t & 3) * 16;

    f32x4 acc[2][4];
    #pragma unroll
    for (int i = 0; i < 2; ++i)
        #pragma unroll
        for (int j = 0; j < 4; ++j) acc[i][j] = (f32x4){0.f, 0.f, 0.f, 0.f};

    for (int d0 = 0; d0 < Dc; d0 += 64) {
        __syncthreads();
        #pragma unroll
        for (int i = 0; i < 2; ++i) {
            int r = sr4 + 64 * i;
            const short* s = &A[(size_t)(m0 + r) * Dc + d0 + sc4];
            *(bf16x8*)&as_[r * 72 + sc4]     = *(const bf16x8*)s;
            *(bf16x8*)&as_[r * 72 + sc4 + 8] = *(const bf16x8*)(s + 8);
        }
        {
            const short* s = &WoT[(size_t)(n0 + sr4) * Dc + d0 + sc4];
            *(bf16x8*)&ws[sr4 * 72 + sc4]     = *(const bf16x8*)s;
            *(bf16x8*)&ws[sr4 * 72 + sc4 + 8] = *(const bf16x8*)(s + 8);
        }
        __syncthreads();
        #pragma unroll
        for (int kc = 0; kc < 64; kc += 32) {
            bf16x8 afr[2], bfr[4];
            #pragma unroll
            for (int ms = 0; ms < 2; ++ms)
                afr[ms] = *(const bf16x8*)&as_[(w * 32 + ms * 16 + l15) * 72 + kc + g * 8];
            #pragma unroll
            for (int nb = 0; nb < 4; ++nb)
                bfr[nb] = *(const bf16x8*)&ws[(nb * 16 + l15) * 72 + kc + g * 8];
            #pragma unroll
            for (int ms = 0; ms < 2; ++ms)
                #pragma unroll
                for (int nb = 0; nb < 4; ++nb)
                    acc[ms][nb] = MFMA16(afr[ms], bfr[nb], acc[ms][nb]);
        }
    }

    #pragma unroll
    for (int ms = 0; ms < 2; ++ms)
        #pragma unroll
        for (int nb = 0; nb < 4; ++nb)
            #pragma unroll
            for (int r = 0; r < 4; ++r)
                out[(size_t)(m0 + w * 32 + ms * 16 + g * 4 + r) * 1024
                    + n0 + nb * 16 + l15] = acc[ms][nb][r];
}

// ---------------------------------------------------------------------------
extern "C" void kernel_launch(void* const* d_in, const int* in_sizes, int n_in,
                              void* d_out, int out_size, void* d_ws, size_t ws_size,
                              hipStream_t stream) {
    (void)in_sizes; (void)n_in; (void)out_size; (void)ws_size;
    const float* q  = (const float*)d_in[0];
    const float* k  = (const float*)d_in[1];
    const float* v  = (const float*)d_in[2];
    const float* Wq = (const float*)d_in[3];
    const float* Wk = (const float*)d_in[4];
    const float* Wv = (const float*)d_in[5];
    const float* Wo = (const float*)d_in[6];
    float* out = (float*)d_out;

    // ws layout (shorts unless noted):
    // Xb[3*4096*1024] | Q | K | Vt | O4 (4M each) | WqT|WkT|WvT (1M each) | WoT (1M)
    // | mrow (f32, 64K)   => 64.25 MiB total
    short* Xb  = (short*)d_ws;
    short* Qw  = Xb  + (size_t)3 * 4096 * Dc;
    short* Kw  = Qw  + BHSF;
    short* Vt  = Kw  + BHSF;
    short* O4  = Vt  + BHSF;
    short* WqT = O4  + BHSF;
    short* WkT = WqT + Hc * Dc * Fc;
    short* WvT = WkT + Hc * Dc * Fc;
    short* WoT = WvT + Hc * Dc * Fc;
    float* mw  = (float*)(WoT + Dc * Dc);

    xcvt_kernel<<<dim3(1024, 3), 256, 0, stream>>>(q, k, v, Xb);
    tcvt_kernel<<<dim3(16, 1, 16), 256, 0, stream>>>(Wq, WqT, Dc, Fc);
    tcvt_kernel<<<dim3(16, 1, 16), 256, 0, stream>>>(Wk, WkT, Dc, Fc);
    tcvt_kernel<<<dim3(16, 1, 16), 256, 0, stream>>>(Wv, WvT, Dc, Fc);
    tcvt_kernel<<<dim3(16, 16, 1), 256, 0, stream>>>(Wo, WoT, Dc, Dc);
    proj_kernel<<<dim3(16, 16, 3), 256, 0, stream>>>(Xb, WqT, WkT, WvT, Qw, Kw, Vt);
    stats_kernel<<<dim3(16, 32), 256, 0, stream>>>(Qw, Kw, mw);
    attn_kernel<<<dim3(16, 32), 256, 0, stream>>>(Qw, Kw, Vt, mw, O4);
    outgemm_kernel<<<dim3(32, 16), 256, 0, stream>>>(O4, WoT, out);
}

// Round 5
// 187.519 us; speedup vs baseline: 12.7217x; 1.1226x over previous
//
#include <hip/hip_runtime.h>
#include <stdint.h>

// Problem dims (fixed)
#define Bc 2
#define Sc 2048
#define Dc 1024
#define Hc 16
#define Fc 64
constexpr int BHSF = Bc * Hc * Sc * Fc;   // 4,194,304

typedef __attribute__((ext_vector_type(8))) short bf16x8;   // MFMA A/B frag (4 VGPR)
typedef __attribute__((ext_vector_type(4))) short bf16x4;
typedef __attribute__((ext_vector_type(4))) float f32x4;    // MFMA C/D frag

#define MFMA16(a, b, c) __builtin_amdgcn_mfma_f32_16x16x32_bf16(a, b, c, 0, 0, 0)
#define EXP2(x) __builtin_amdgcn_exp2f(x)
#define SCALE2 0.18033688f   /* 0.125 * log2(e) : softmax in base-2 domain */

__device__ inline short f2bf(float x) {           // fp32 -> bf16 rne
    uint32_t u = __builtin_bit_cast(uint32_t, x);
    u = (u + 0x7fffu + ((u >> 16) & 1u)) >> 16;
    return (short)u;
}

// ---------------------------------------------------------------------------
// K0a: elementwise fp32 -> bf16 for q,k,v into Xb[3][4096][1024]
// ---------------------------------------------------------------------------
__global__ __launch_bounds__(256) void xcvt_kernel(
    const float* __restrict__ a, const float* __restrict__ b,
    const float* __restrict__ c, short* __restrict__ out)
{
    const float* src = (blockIdx.y == 0) ? a : (blockIdx.y == 1) ? b : c;
    const size_t base = (size_t)blockIdx.x * 4096 + threadIdx.x * 16;
    const float* s = src + base;
    short* d = out + (size_t)blockIdx.y * 4096 * 1024 + base;
    f32x4 v0 = ((const f32x4*)s)[0], v1 = ((const f32x4*)s)[1];
    f32x4 v2 = ((const f32x4*)s)[2], v3 = ((const f32x4*)s)[3];
    bf16x8 p0, p1;
    #pragma unroll
    for (int i = 0; i < 4; ++i) {
        p0[i] = f2bf(v0[i]); p0[4 + i] = f2bf(v1[i]);
        p1[i] = f2bf(v2[i]); p1[4 + i] = f2bf(v3[i]);
    }
    *(bf16x8*)d       = p0;
    *(bf16x8*)(d + 8) = p1;
}

// ---------------------------------------------------------------------------
// K0b: transpose+cvt for the 3 QKV weights in ONE launch.
// z = blockIdx.z: sel = z>>4 (Wq/Wk/Wv), h = z&15. [1024][64] -> [64][1024].
// ---------------------------------------------------------------------------
__global__ __launch_bounds__(256) void tcvt3_kernel(
    const float* __restrict__ Wq, const float* __restrict__ Wk,
    const float* __restrict__ Wv,
    short* __restrict__ WqT, short* __restrict__ WkT, short* __restrict__ WvT)
{
    __shared__ short td[64 * 72];
    const int t = threadIdx.x;
    const int sr = t >> 2, sc = (t & 3) * 16;
    const int sel = blockIdx.z >> 4, h = blockIdx.z & 15;
    const int m0 = blockIdx.x * 64;
    const float* in = ((sel == 0) ? Wq : (sel == 1) ? Wk : Wv) + (size_t)h * Dc * Fc;
    short* out = ((sel == 0) ? WqT : (sel == 1) ? WkT : WvT) + (size_t)h * Fc * Dc;

    const float* src = in + (size_t)(m0 + sr) * Fc + sc;
    #pragma unroll
    for (int i = 0; i < 16; i += 4) {
        f32x4 a = *(const f32x4*)(src + i);
        td[sr * 72 + sc + i + 0] = f2bf(a[0]);
        td[sr * 72 + sc + i + 1] = f2bf(a[1]);
        td[sr * 72 + sc + i + 2] = f2bf(a[2]);
        td[sr * 72 + sc + i + 3] = f2bf(a[3]);
    }
    __syncthreads();
    alignas(16) short vals[16];
    #pragma unroll
    for (int i = 0; i < 16; ++i) vals[i] = td[(sc + i) * 72 + sr];
    short* dst = out + (size_t)sr * Dc + m0 + sc;
    *(bf16x8*)dst       = *(const bf16x8*)&vals[0];
    *(bf16x8*)(dst + 8) = *(const bf16x8*)&vals[8];
}

// ---------------------------------------------------------------------------
// K0c: transpose+cvt Wo [1024][1024] -> WoT [1024][1024]
// ---------------------------------------------------------------------------
__global__ __launch_bounds__(256) void tcvt_kernel(
    const float* __restrict__ in, short* __restrict__ out, int M, int N)
{
    __shared__ short td[64 * 72];
    const int t = threadIdx.x;
    const int sr = t >> 2, sc = (t & 3) * 16;
    const int m0 = blockIdx.x * 64, n0 = blockIdx.y * 64;

    const float* src = in + (size_t)(m0 + sr) * N + n0 + sc;
    #pragma unroll
    for (int i = 0; i < 16; i += 4) {
        f32x4 a = *(const f32x4*)(src + i);
        td[sr * 72 + sc + i + 0] = f2bf(a[0]);
        td[sr * 72 + sc + i + 1] = f2bf(a[1]);
        td[sr * 72 + sc + i + 2] = f2bf(a[2]);
        td[sr * 72 + sc + i + 3] = f2bf(a[3]);
    }
    __syncthreads();
    alignas(16) short vals[16];
    #pragma unroll
    for (int i = 0; i < 16; ++i) vals[i] = td[(sc + i) * 72 + sr];
    short* dst = out + (size_t)(n0 + sr) * M + m0 + sc;
    *(bf16x8*)dst       = *(const bf16x8*)&vals[0];
    *(bf16x8*)(dst + 8) = *(const bf16x8*)&vals[8];
}

// ---------------------------------------------------------------------------
// K1: QKV projection. NT MFMA, single-barrier double-buffered K-loop.
// m-tile 128 (msub=2), BK=64. h fastest grid dim (L2 sharing of x slab).
// z=0 Q rows, z=1 K rows, z=2 V transposed [b,h,f,s].
// grid (16 h, 32 mt, 3 z), 256 thr.
// ---------------------------------------------------------------------------
__global__ __launch_bounds__(256) void proj_kernel(
    const short* __restrict__ Xb,
    const short* __restrict__ WqT, const short* __restrict__ WkT,
    const short* __restrict__ WvT,
    short* __restrict__ Qo, short* __restrict__ Ko, short* __restrict__ VtO)
{
    const int z = blockIdx.z, h = blockIdx.x, mt = blockIdx.y;
    const short* X  = Xb + (size_t)z * 4096 * Dc;
    const short* Wt = ((z == 0) ? WqT : (z == 1) ? WkT : WvT) + (size_t)h * Fc * Dc;
    const int m0 = mt * 128;

    __shared__ short xsA[128 * 72], xsB[128 * 72];
    __shared__ short wsA[64 * 72],  wsB[64 * 72];

    const int t = threadIdx.x, lane = t & 63, w = t >> 6;
    const int l15 = lane & 15, g = lane >> 4;
    const int xr = t >> 1, xc = (t & 1) * 32;     // X staging: 4 bf16x8/thread
    const int wr = t >> 2, wc = (t & 3) * 16;     // W staging: 2 bf16x8/thread

    bf16x8 xg[4], wg[2];
    auto gload = [&](int d0) {
        const short* s = &X[(size_t)(m0 + xr) * Dc + d0 + xc];
        #pragma unroll
        for (int j = 0; j < 4; ++j) xg[j] = *(const bf16x8*)(s + 8 * j);
        const short* ww = &Wt[(size_t)wr * Dc + d0 + wc];
        wg[0] = *(const bf16x8*)ww;
        wg[1] = *(const bf16x8*)(ww + 8);
    };
    auto swrite = [&](short* xsD, short* wsD) {
        #pragma unroll
        for (int j = 0; j < 4; ++j) *(bf16x8*)&xsD[xr * 72 + xc + 8 * j] = xg[j];
        *(bf16x8*)&wsD[wr * 72 + wc]     = wg[0];
        *(bf16x8*)&wsD[wr * 72 + wc + 8] = wg[1];
    };

    f32x4 acc[2][4];
    #pragma unroll
    for (int i = 0; i < 2; ++i)
        #pragma unroll
        for (int j = 0; j < 4; ++j) acc[i][j] = (f32x4){0.f, 0.f, 0.f, 0.f};

    gload(0); swrite(xsA, wsA); gload(64);

    auto half = [&](int d0, const short* xsC, const short* wsC,
                    short* xsN, short* wsN) {
        __syncthreads();
        if (d0 + 64 < Dc) swrite(xsN, wsN);
        if (d0 + 128 < Dc) gload(d0 + 128);
        #pragma unroll
        for (int kc = 0; kc < 64; kc += 32) {
            bf16x8 afr[2], bfr[4];
            #pragma unroll
            for (int ms = 0; ms < 2; ++ms)
                afr[ms] = *(const bf16x8*)&xsC[(w * 32 + ms * 16 + l15) * 72 + kc + g * 8];
            #pragma unroll
            for (int fb = 0; fb < 4; ++fb)
                bfr[fb] = *(const bf16x8*)&wsC[(fb * 16 + l15) * 72 + kc + g * 8];
            #pragma unroll
            for (int ms = 0; ms < 2; ++ms)
                #pragma unroll
                for (int fb = 0; fb < 4; ++fb)
                    acc[ms][fb] = MFMA16(afr[ms], bfr[fb], acc[ms][fb]);
        }
    };

    for (int d0 = 0; d0 < Dc; d0 += 128) {
        half(d0,      xsA, wsA, xsB, wsB);
        half(d0 + 64, xsB, wsB, xsA, wsA);
    }

    // bounce accs through xsA (viewed [128][72]) for coalesced stores
    __syncthreads();
    #pragma unroll
    for (int ms = 0; ms < 2; ++ms)
        #pragma unroll
        for (int fb = 0; fb < 4; ++fb)
            #pragma unroll
            for (int r = 0; r < 4; ++r)
                xsA[(w * 32 + ms * 16 + g * 4 + r) * 72 + fb * 16 + l15] =
                    f2bf(acc[ms][fb][r]);
    __syncthreads();

    const int b = m0 >> 11, s0 = m0 & 2047;
    if (z < 2) {
        short* outp = ((z == 0) ? Qo : Ko) + ((size_t)(b * Hc + h) * Sc + s0) * Fc;
        #pragma unroll
        for (int j = 0; j < 4; ++j)
            *(bf16x8*)&outp[(size_t)xr * Fc + xc + 8 * j] =
                *(const bf16x8*)&xsA[xr * 72 + xc + 8 * j];
    } else {
        // Vt[b,h,f,s]: thread owns f = t>>2, 32 s-cols (gather = transpose)
        const int fr = t >> 2, sc0 = (t & 3) * 32;
        short* o = VtO + ((size_t)(b * Hc + h) * Fc + fr) * Sc + s0 + sc0;
        alignas(16) short vals[32];
        #pragma unroll
        for (int j = 0; j < 32; ++j) vals[j] = xsA[(sc0 + j) * 72 + fr];
        #pragma unroll
        for (int j = 0; j < 4; ++j)
            *(bf16x8*)(o + 8 * j) = *(const bf16x8*)&vals[8 * j];
    }
}

// ---------------------------------------------------------------------------
// K2: softmax stats. S^T = mfma(K rows, Q rows); lane col = q. Single-barrier
// dbuf on K staging. Writes fused m' = m + log2(l).
// grid (16 q-tiles of 128, 32 bh), 256 thr.
// ---------------------------------------------------------------------------
__global__ __launch_bounds__(256) void stats_kernel(
    const short* __restrict__ Qg, const short* __restrict__ Kg,
    float* __restrict__ mrow)
{
    const int q0 = blockIdx.x * 128;
    const int bh = blockIdx.y;
    const short* Qb = Qg + (size_t)bh * Sc * Fc;
    const short* Kb = Kg + (size_t)bh * Sc * Fc;

    __shared__ short ksA[64 * 72], ksB[64 * 72];

    const int t = threadIdx.x, lane = t & 63, w = t >> 6;
    const int l15 = lane & 15, g = lane >> 4;
    const int sr4 = t >> 2, sc4 = (t & 3) * 16;

    bf16x8 qf[2][2];
    #pragma unroll
    for (int qs2 = 0; qs2 < 2; ++qs2)
        #pragma unroll
        for (int kc2 = 0; kc2 < 2; ++kc2)
            qf[qs2][kc2] = *(const bf16x8*)
                &Qb[(size_t)(q0 + w * 32 + qs2 * 16 + l15) * Fc + kc2 * 32 + g * 8];

    bf16x8 kr0, kr1;
    auto gload = [&](int kt) {
        const short* s = &Kb[(size_t)(kt + sr4) * Fc + sc4];
        kr0 = *(const bf16x8*)s;
        kr1 = *(const bf16x8*)(s + 8);
    };
    auto swrite = [&](short* d) {
        *(bf16x8*)&d[sr4 * 72 + sc4]     = kr0;
        *(bf16x8*)&d[sr4 * 72 + sc4 + 8] = kr1;
    };

    float m[2] = {-1e30f, -1e30f}, l[2] = {0.f, 0.f};

    gload(0); swrite(ksA); gload(64);

    auto half = [&](int kt, const short* cur, short* nxt) {
        __syncthreads();
        if (kt + 64 < Sc) swrite(nxt);
        if (kt + 128 < Sc) gload(kt + 128);
        #pragma unroll
        for (int kf = 0; kf < 4; ++kf) {
            bf16x8 a0 = *(const bf16x8*)&cur[(kf * 16 + l15) * 72 + 0  + g * 8];
            bf16x8 a1 = *(const bf16x8*)&cur[(kf * 16 + l15) * 72 + 32 + g * 8];
            #pragma unroll
            for (int qs2 = 0; qs2 < 2; ++qs2) {
                f32x4 acc = (f32x4){0.f, 0.f, 0.f, 0.f};
                acc = MFMA16(a0, qf[qs2][0], acc);
                acc = MFMA16(a1, qf[qs2][1], acc);   // same f-split order as attn
                float s0 = acc[0] * SCALE2, s1 = acc[1] * SCALE2;
                float s2 = acc[2] * SCALE2, s3 = acc[3] * SCALE2;
                float tm = fmaxf(fmaxf(s0, s1), fmaxf(s2, s3));
                float mn = fmaxf(m[qs2], tm);
                l[qs2] = l[qs2] * EXP2(m[qs2] - mn) + EXP2(s0 - mn) + EXP2(s1 - mn)
                                                    + EXP2(s2 - mn) + EXP2(s3 - mn);
                m[qs2] = mn;
            }
        }
    };

    for (int kt = 0; kt < Sc; kt += 128) {
        half(kt,      ksA, ksB);
        half(kt + 64, ksB, ksA);
    }

    #pragma unroll
    for (int qs2 = 0; qs2 < 2; ++qs2) {
        #pragma unroll
        for (int off = 16; off < 64; off <<= 1) {
            float om = __shfl_xor(m[qs2], off, 64);
            float ol = __shfl_xor(l[qs2], off, 64);
            float mn = fmaxf(m[qs2], om);
            l[qs2] = l[qs2] * EXP2(m[qs2] - mn) + ol * EXP2(om - mn);
            m[qs2] = mn;
        }
        if (lane < 16)
            mrow[bh * Sc + q0 + w * 32 + qs2 * 16 + l15] = m[qs2] + __log2f(l[qs2]);
    }
}

// ---------------------------------------------------------------------------
// K3: O4[b,h,k,f] = sum_q P[q,k] V[q,f].  S-orientation: S = mfma(Q,K) ->
// C row=q, col=k -> P^T written with b64 packed stores. Reg-staged dbuf on
// Q/Vt (loads issued 2 chunks ahead). PV: A = P^T rows, B = Vt rows.
// grid (16 k-tiles of 128, 32 bh), 256 thr.
// ---------------------------------------------------------------------------
__global__ __launch_bounds__(256) void attn_kernel(
    const short* __restrict__ Qg, const short* __restrict__ Kg,
    const short* __restrict__ VtG, const float* __restrict__ mrow,
    short* __restrict__ O4)
{
    const int k0 = blockIdx.x * 128;
    const int bh = blockIdx.y;
    const short* Qb = Qg  + (size_t)bh * Sc * Fc;
    const short* Kb = Kg  + (size_t)bh * Sc * Fc;
    const short* Vb = VtG + (size_t)bh * Fc * Sc;   // [64 f][2048 s]
    const float* mb = mrow + (size_t)bh * Sc;

    __shared__ short qsA[64 * 72], qsB[64 * 72];
    __shared__ short vtA[64 * 72], vtB[64 * 72];
    __shared__ short pl[128 * 72];   // P^T [k-local][q-chunk]; reused as out-bounce

    const int t = threadIdx.x, lane = t & 63, w = t >> 6;
    const int l15 = lane & 15, g = lane >> 4;
    const int sr4 = t >> 2, sc4 = (t & 3) * 16;

    // resident K B-frags: wave w owns k-cols k0 + w*32 + ks2*16 + l15
    bf16x8 kf[2][2];
    #pragma unroll
    for (int ks2 = 0; ks2 < 2; ++ks2)
        #pragma unroll
        for (int kc2 = 0; kc2 < 2; ++kc2)
            kf[ks2][kc2] = *(const bf16x8*)
                &Kb[(size_t)(k0 + w * 32 + ks2 * 16 + l15) * Fc + kc2 * 32 + g * 8];

    f32x4 oacc[2][4];
    #pragma unroll
    for (int i = 0; i < 2; ++i)
        #pragma unroll
        for (int j = 0; j < 4; ++j) oacc[i][j] = (f32x4){0.f, 0.f, 0.f, 0.f};

    bf16x8 qr0, qr1, vr0, vr1;
    auto gload = [&](int qn) {
        const short* s = &Qb[(size_t)(qn + sr4) * Fc + sc4];
        qr0 = *(const bf16x8*)s;
        qr1 = *(const bf16x8*)(s + 8);
        const short* v = &Vb[(size_t)sr4 * Sc + qn + sc4];
        vr0 = *(const bf16x8*)v;
        vr1 = *(const bf16x8*)(v + 8);
    };
    auto swrite = [&](short* qsD, short* vtD) {
        *(bf16x8*)&qsD[sr4 * 72 + sc4]     = qr0;
        *(bf16x8*)&qsD[sr4 * 72 + sc4 + 8] = qr1;
        *(bf16x8*)&vtD[sr4 * 72 + sc4]     = vr0;
        *(bf16x8*)&vtD[sr4 * 72 + sc4 + 8] = vr1;
    };

    gload(0); swrite(qsA, vtA); gload(64);

    auto chunk = [&](int q0, const short* qsC, const short* vtC,
                     short* qsN, short* vtN) {
        __syncthreads();                 // buf[cur] ready; pl readers done
        if (q0 + 64 < Sc) swrite(qsN, vtN);
        if (q0 + 128 < Sc) gload(q0 + 128);

        // phase A: S = mfma(Q,K); row=q (g*4+r), col=k (l15). P^T b64 writes.
        f32x4 mq[4];
        #pragma unroll
        for (int qf = 0; qf < 4; ++qf)
            mq[qf] = *(const f32x4*)&mb[q0 + qf * 16 + g * 4];
        #pragma unroll
        for (int qf = 0; qf < 4; ++qf) {
            bf16x8 qa0 = *(const bf16x8*)&qsC[(qf * 16 + l15) * 72 + 0  + g * 8];
            bf16x8 qa1 = *(const bf16x8*)&qsC[(qf * 16 + l15) * 72 + 32 + g * 8];
            #pragma unroll
            for (int ks2 = 0; ks2 < 2; ++ks2) {
                f32x4 acc = (f32x4){0.f, 0.f, 0.f, 0.f};
                acc = MFMA16(qa0, kf[ks2][0], acc);
                acc = MFMA16(qa1, kf[ks2][1], acc);
                bf16x4 pv;
                #pragma unroll
                for (int r = 0; r < 4; ++r)
                    pv[r] = f2bf(EXP2(acc[r] * SCALE2 - mq[qf][r]));
                *(bf16x4*)&pl[(w * 32 + ks2 * 16 + l15) * 72 + qf * 16 + g * 4] = pv;
            }
        }
        __syncthreads();                 // P^T visible

        // phase B: PV.  A = P^T rows (k), B = Vt rows (f). C[k-row][f-col].
        #pragma unroll
        for (int qc = 0; qc < 64; qc += 32) {
            bf16x8 pa[2], vbf[4];
            #pragma unroll
            for (int ks2 = 0; ks2 < 2; ++ks2)
                pa[ks2] = *(const bf16x8*)&pl[(w * 32 + ks2 * 16 + l15) * 72 + qc + g * 8];
            #pragma unroll
            for (int fb = 0; fb < 4; ++fb)
                vbf[fb] = *(const bf16x8*)&vtC[(fb * 16 + l15) * 72 + qc + g * 8];
            #pragma unroll
            for (int ks2 = 0; ks2 < 2; ++ks2)
                #pragma unroll
                for (int fb = 0; fb < 4; ++fb)
                    oacc[ks2][fb] = MFMA16(pa[ks2], vbf[fb], oacc[ks2][fb]);
        }
    };

    for (int q0 = 0; q0 < Sc; q0 += 128) {
        chunk(q0,      qsA, vtA, qsB, vtB);
        chunk(q0 + 64, qsB, vtB, qsA, vtA);
    }

    // epilogue: bounce via pl for coalesced bf16 stores (128 rows x 64)
    __syncthreads();
    #pragma unroll
    for (int ks2 = 0; ks2 < 2; ++ks2)
        #pragma unroll
        for (int fb = 0; fb < 4; ++fb)
            #pragma unroll
            for (int r = 0; r < 4; ++r)
                pl[(w * 32 + ks2 * 16 + g * 4 + r) * 72 + fb * 16 + l15] =
                    f2bf(oacc[ks2][fb][r]);
    __syncthreads();
    {
        const int sr2 = t >> 1, sc2 = (t & 1) * 32;
        short* o = O4 + ((size_t)bh * Sc + k0 + sr2) * Fc + sc2;
        #pragma unroll
        for (int i = 0; i < 32; i += 8)
            *(bf16x8*)&o[i] = *(const bf16x8*)&pl[sr2 * 72 + sc2 + i];
    }
}

// ---------------------------------------------------------------------------
// K4: out(fp32) = O4 (flat [4096][1024] bf16) @ Wo. NT, single-barrier dbuf.
// m-tile 128 (msub=2). grid (32 mt, 16 nt), 256 thr.
// ---------------------------------------------------------------------------
__global__ __launch_bounds__(256) void outgemm_kernel(
    const short* __restrict__ A, const short* __restrict__ WoT,
    float* __restrict__ out)
{
    const int m0 = blockIdx.x * 128, n0 = blockIdx.y * 64;

    __shared__ short asA[128 * 72], asB[128 * 72];
    __shared__ short wsA[64 * 72],  wsB[64 * 72];

    const int t = threadIdx.x, lane = t & 63, w = t >> 6;
    const int l15 = lane & 15, g = lane >> 4;
    const int ar = t >> 1, ac = (t & 1) * 32;
    const int wr = t >> 2, wc = (t & 3) * 16;

    bf16x8 ag[4], wg[2];
    auto gload = [&](int d0) {
        const short* s = &A[(size_t)(m0 + ar) * Dc + d0 + ac];
        #pragma unroll
        for (int j = 0; j < 4; ++j) ag[j] = *(const bf16x8*)(s + 8 * j);
        const short* ww = &WoT[(size_t)(n0 + wr) * Dc + d0 + wc];
        wg[0] = *(const bf16x8*)ww;
        wg[1] = *(const bf16x8*)(ww + 8);
    };
    auto swrite = [&](short* asD, short* wsD) {
        #pragma unroll
        for (int j = 0; j < 4; ++j) *(bf16x8*)&asD[ar * 72 + ac + 8 * j] = ag[j];
        *(bf16x8*)&wsD[wr * 72 + wc]     = wg[0];
        *(bf16x8*)&wsD[wr * 72 + wc + 8] = wg[1];
    };

    f32x4 acc[2][4];
    #pragma unroll
    for (int i = 0; i < 2; ++i)
        #pragma unroll
        for (int j = 0; j < 4; ++j) acc[i][j] = (f32x4){0.f, 0.f, 0.f, 0.f};

    gload(0); swrite(asA, wsA); gload(64);

    auto half = [&](int d0, const short* asC, const short* wsC,
                    short* asN, short* wsN) {
        __syncthreads();
        if (d0 + 64 < Dc) swrite(asN, wsN);
        if (d0 + 128 < Dc) gload(d0 + 128);
        #pragma unroll
        for (int kc = 0; kc < 64; kc += 32) {
            bf16x8 afr[2], bfr[4];
            #pragma unroll
            for (int ms = 0; ms < 2; ++ms)
                afr[ms] = *(const bf16x8*)&asC[(w * 32 + ms * 16 + l15) * 72 + kc + g * 8];
            #pragma unroll
            for (int nb = 0; nb < 4; ++nb)
                bfr[nb] = *(const bf16x8*)&wsC[(nb * 16 + l15) * 72 + kc + g * 8];
            #pragma unroll
            for (int ms = 0; ms < 2; ++ms)
                #pragma unroll
                for (int nb = 0; nb < 4; ++nb)
                    acc[ms][nb] = MFMA16(afr[ms], bfr[nb], acc[ms][nb]);
        }
    };

    for (int d0 = 0; d0 < Dc; d0 += 128) {
        half(d0,      asA, wsA, asB, wsB);
        half(d0 + 64, asB, wsB, asA, wsA);
    }

    #pragma unroll
    for (int ms = 0; ms < 2; ++ms)
        #pragma unroll
        for (int nb = 0; nb < 4; ++nb)
            #pragma unroll
            for (int r = 0; r < 4; ++r)
                out[(size_t)(m0 + w * 32 + ms * 16 + g * 4 + r) * 1024
                    + n0 + nb * 16 + l15] = acc[ms][nb][r];
}

// ---------------------------------------------------------------------------
extern "C" void kernel_launch(void* const* d_in, const int* in_sizes, int n_in,
                              void* d_out, int out_size, void* d_ws, size_t ws_size,
                              hipStream_t stream) {
    (void)in_sizes; (void)n_in; (void)out_size; (void)ws_size;
    const float* q  = (const float*)d_in[0];
    const float* k  = (const float*)d_in[1];
    const float* v  = (const float*)d_in[2];
    const float* Wq = (const float*)d_in[3];
    const float* Wk = (const float*)d_in[4];
    const float* Wv = (const float*)d_in[5];
    const float* Wo = (const float*)d_in[6];
    float* out = (float*)d_out;

    // ws layout (shorts unless noted):
    // Xb[3*4096*1024] | Q | K | Vt | O4 (4M each) | WqT|WkT|WvT (1M each) | WoT (1M)
    // | mrow (f32, 64K)   => 64.25 MiB total
    short* Xb  = (short*)d_ws;
    short* Qw  = Xb  + (size_t)3 * 4096 * Dc;
    short* Kw  = Qw  + BHSF;
    short* Vt  = Kw  + BHSF;
    short* O4  = Vt  + BHSF;
    short* WqT = O4  + BHSF;
    short* WkT = WqT + Hc * Dc * Fc;
    short* WvT = WkT + Hc * Dc * Fc;
    short* WoT = WvT + Hc * Dc * Fc;
    float* mw  = (float*)(WoT + Dc * Dc);

    xcvt_kernel<<<dim3(1024, 3), 256, 0, stream>>>(q, k, v, Xb);
    tcvt3_kernel<<<dim3(16, 1, 48), 256, 0, stream>>>(Wq, Wk, Wv, WqT, WkT, WvT);
    tcvt_kernel<<<dim3(16, 16, 1), 256, 0, stream>>>(Wo, WoT, Dc, Dc);
    proj_kernel<<<dim3(16, 32, 3), 256, 0, stream>>>(Xb, WqT, WkT, WvT, Qw, Kw, Vt);
    stats_kernel<<<dim3(16, 32), 256, 0, stream>>>(Qw, Kw, mw);
    attn_kernel<<<dim3(16, 32), 256, 0, stream>>>(Qw, Kw, Vt, mw, O4);
    outgemm_kernel<<<dim3(32, 16), 256, 0, stream>>>(O4, WoT, out);
}